// Round 5
// baseline (157.785 us; speedup 1.0000x reference)
//
#include <hip/hip_runtime.h>
#include <math.h>

#define N_ROWS 524288
#define H_COLS 256
#define G_SEGS 8192
#define WS_BLOCKS 1024              // 4096 persistent waves, ~2 segments each
#define N_WAVES (WS_BLOCKS * 4)

// Kernel 1: find segment start offsets from sorted pair_ids; also resets the
// work-stealing counter (stream-ordered before seg_lse reads it).
__global__ __launch_bounds__(256) void find_starts(const int* __restrict__ ids,
                                                   int* __restrict__ starts,
                                                   int* __restrict__ counter, int n) {
    int i = blockIdx.x * blockDim.x + threadIdx.x;
    if (i >= n) return;
    int id = ids[i];
    if (i == 0) {
        starts[id] = 0;
        starts[G_SEGS] = n;
        *counter = N_WAVES;         // first N_WAVES tasks are taken statically
    } else if (ids[i - 1] != id) {
        starts[id] = i;
    }
}

// Kernel 2: persistent waves, work-stealing over segments. Per segment the
// body is identical to the best-so-far R2 kernel: lane l owns columns
// [4l,4l+3] (float4), shift fixed from the segment's first row (LSE
// shift-invariance), loop body = sub+exp+add with only the add loop-carried,
// unroll 4 for 4 independent 16B loads in flight. Work-stealing removes
// CU-level imbalance (32 Poisson-length segments per CU) and the long-segment
// drain tail.
__global__ __launch_bounds__(256) void seg_lse(const float* __restrict__ x,
                                               const int* __restrict__ starts,
                                               float* __restrict__ out,
                                               int* __restrict__ counter) {
    const int wave = threadIdx.x >> 6;
    const int lane = threadIdx.x & 63;
    const float4* __restrict__ xp = reinterpret_cast<const float4*>(x) + lane;

    int g = blockIdx.x * 4 + wave;  // static first task: no t=0 atomic burst

    while (g < G_SEGS) {
        const int s0 = starts[g];
        const int s1 = starts[g + 1];

        // Peel row s0: defines the shift; its own contribution is exp(0)=1.
        float4 mv = xp[(size_t)s0 * (H_COLS / 4)];
        const float m0 = mv.x, m1 = mv.y, m2 = mv.z, m3 = mv.w;
        float a0 = 1.f, a1 = 1.f, a2 = 1.f, a3 = 1.f;

#pragma unroll 4
        for (int r = s0 + 1; r < s1; ++r) {
            float4 v = xp[(size_t)r * (H_COLS / 4)];
            a0 += __expf(v.x - m0);
            a1 += __expf(v.y - m1);
            a2 += __expf(v.z - m2);
            a3 += __expf(v.w - m3);
        }

        float4 o;
        o.x = m0 + logf(a0);
        o.y = m1 + logf(a1);
        o.z = m2 + logf(a2);
        o.w = m3 + logf(a3);
        reinterpret_cast<float4*>(out)[(size_t)g * (H_COLS / 4) + lane] = o;

        // Steal the next segment.
        int t;
        if (lane == 0) t = atomicAdd(counter, 1);
        g = __shfl(t, 0, 64);
    }
}

extern "C" void kernel_launch(void* const* d_in, const int* in_sizes, int n_in,
                              void* d_out, int out_size, void* d_ws, size_t ws_size,
                              hipStream_t stream) {
    const float* seq_rep = (const float*)d_in[0];
    const int* pair_ids = (const int*)d_in[1];
    float* out = (float*)d_out;
    int* starts = (int*)d_ws;               // G_SEGS + 1 ints
    int* counter = starts + (G_SEGS + 1);   // 1 int

    int n = in_sizes[1];  // N_ROWS

    find_starts<<<(n + 255) / 256, 256, 0, stream>>>(pair_ids, starts, counter, n);
    seg_lse<<<WS_BLOCKS, 256, 0, stream>>>(seq_rep, starts, out, counter);
}

// Round 6
// 113.043 us; speedup vs baseline: 1.3958x; 1.3958x over previous
//
#include <hip/hip_runtime.h>
#include <math.h>

#define N_ROWS 524288
#define H_COLS 256
#define G_SEGS 8192
#define SEGS_PER_BLOCK 4

// Kernel 1: find segment start offsets from sorted pair_ids.
__global__ __launch_bounds__(256) void find_starts(const int* __restrict__ ids,
                                                   int* __restrict__ starts, int n) {
    int i = blockIdx.x * blockDim.x + threadIdx.x;
    if (i >= n) return;
    int id = ids[i];
    if (i == 0) {
        starts[id] = 0;
        starts[G_SEGS] = n;
    } else if (ids[i - 1] != id) {
        starts[id] = i;
    }
}

// Kernel 2: one wave per segment (8192 waves = exactly 32/CU resident), lane l
// owns columns [4l,4l+3] via float4. Shift fixed from the segment's first row
// (LSE shift-invariance). The kernel is in-flight-bytes limited (R5 evidence:
// halving resident waves cost 1.44x), so unroll 8 keeps 8 independent 16B
// loads in flight per lane. No launch_bounds min-wave spec: R4 showed capping
// VGPR at 64 makes the compiler serialize the pipeline instead.
// exp2(fma(v,log2e,-b)) replaces exp(v-m): 2 VALU ops/element instead of 3.
__global__ __launch_bounds__(256) void seg_lse(const float* __restrict__ x,
                                               const int* __restrict__ starts,
                                               float* __restrict__ out) {
    const int wave = threadIdx.x >> 6;
    const int lane = threadIdx.x & 63;
    const int g = blockIdx.x * SEGS_PER_BLOCK + wave;

    const int s0 = starts[g];
    const int s1 = starts[g + 1];

    const float4* __restrict__ xp = reinterpret_cast<const float4*>(x) + lane;

    // Peel row s0: defines the shift; its own contribution is exp(0)=1.
    float4 mv = xp[(size_t)s0 * (H_COLS / 4)];
    const float m0 = mv.x, m1 = mv.y, m2 = mv.z, m3 = mv.w;
    const float K = 1.44269504088896f;  // log2(e)
    const float b0 = m0 * K, b1 = m1 * K, b2 = m2 * K, b3 = m3 * K;
    float a0 = 1.f, a1 = 1.f, a2 = 1.f, a3 = 1.f;

#pragma unroll 8
    for (int r = s0 + 1; r < s1; ++r) {
        float4 v = xp[(size_t)r * (H_COLS / 4)];
        a0 += exp2f(__builtin_fmaf(v.x, K, -b0));
        a1 += exp2f(__builtin_fmaf(v.y, K, -b1));
        a2 += exp2f(__builtin_fmaf(v.z, K, -b2));
        a3 += exp2f(__builtin_fmaf(v.w, K, -b3));
    }

    float4 o;
    o.x = m0 + logf(a0);
    o.y = m1 + logf(a1);
    o.z = m2 + logf(a2);
    o.w = m3 + logf(a3);
    reinterpret_cast<float4*>(out)[(size_t)g * (H_COLS / 4) + lane] = o;
}

extern "C" void kernel_launch(void* const* d_in, const int* in_sizes, int n_in,
                              void* d_out, int out_size, void* d_ws, size_t ws_size,
                              hipStream_t stream) {
    const float* seq_rep = (const float*)d_in[0];
    const int* pair_ids = (const int*)d_in[1];
    float* out = (float*)d_out;
    int* starts = (int*)d_ws;  // G_SEGS + 1 ints

    int n = in_sizes[1];  // N_ROWS

    find_starts<<<(n + 255) / 256, 256, 0, stream>>>(pair_ids, starts, n);
    seg_lse<<<G_SEGS / SEGS_PER_BLOCK, 256, 0, stream>>>(seq_rep, starts, out);
}